// Round 5
// baseline (560.509 us; speedup 1.0000x reference)
//
#include <hip/hip_runtime.h>

#define B_   32
#define HW_  196
#define C_   512
#define M_   (B_*HW_)    // 6272
#define HID_ 128
#define NBLK 18

typedef _Float16 f16;
typedef _Float16 f16x8 __attribute__((ext_vector_type(8)));
typedef float    f32x4 __attribute__((ext_vector_type(4)));

__device__ __forceinline__ float gelu_f(float x) {
    float t = tanhf(0.7978845608028654f * (x + 0.044715f * x * x * x));
    return 0.5f * x * (1.0f + t);
}

// async global->LDS, 16B per lane; LDS dest = wave-uniform base + lane*16
__device__ __forceinline__ void gl16(const void* g, void* l) {
    __builtin_amdgcn_global_load_lds((const __attribute__((address_space(1))) unsigned*)g,
                                     (__attribute__((address_space(3))) unsigned*)l, 16, 0, 0);
}

// ---------- weights: fp32 [blk][k][n] -> fp16 transposed [blk][n][k] ----------
__global__ __launch_bounds__(256) void conv_w(const float* __restrict__ W,
                                              f16* __restrict__ Wt) {
    __shared__ f16 sh[64][72];
    const int blk = blockIdx.z, k0 = blockIdx.x * 64, n0 = blockIdx.y * 64;
    const int tid = threadIdx.x;
    const float* Wb = W + (size_t)blk * C_ * C_;
    #pragma unroll
    for (int i = 0; i < 4; ++i) {
        int s = tid + i * 256, r = s >> 4, c4 = (s & 15) << 2;
        float4 v = *(const float4*)&Wb[(size_t)(k0 + r) * C_ + n0 + c4];
        sh[r][c4 + 0] = (f16)v.x; sh[r][c4 + 1] = (f16)v.y;
        sh[r][c4 + 2] = (f16)v.z; sh[r][c4 + 3] = (f16)v.w;
    }
    __syncthreads();
    #pragma unroll
    for (int i = 0; i < 2; ++i) {
        int s = tid + i * 256, r = s >> 3, c8 = (s & 7) << 3;
        f16x8 o;
        #pragma unroll
        for (int j = 0; j < 8; ++j) o[j] = sh[c8 + j][r];
        *(f16x8*)&Wt[(size_t)blk * C_ * C_ + (size_t)(n0 + r) * C_ + k0 + c8] = o;
    }
}

// ---------- x: fp32 -> fp16 ----------
__global__ __launch_bounds__(256) void conv_x(const float* __restrict__ in,
                                              f16* __restrict__ out) {
    int i = blockIdx.x * 256 + threadIdx.x;
    out[i] = (f16)in[i];
}

// ---------- MFMA GEMM: out = gelu(A[M,K]@W_blk[K,N] + b) ----------
// 128x128x64 tile, 4 waves (2x2, each 64x64 of 4x4 16x16x32 frags),
// global_load_lds staging with XOR-16B swizzle, double-buffered LDS.
#define BM 128
#define BN 128
#define BK 64
// LDS layout (halfs): tile[r][c-block] at r*64 + ((c ^ (r&7))<<3), r<128, c<8
__global__ __launch_bounds__(256) void gemm_f16(
    const f16* __restrict__ A, const f16* __restrict__ Wt,
    const float* __restrict__ ball, int blk, f16* __restrict__ out)
{
    __shared__ f16 As[2][BM * BK];
    __shared__ f16 Ws[2][BN * BK];
    const int tid = threadIdx.x;
    const int wave = tid >> 6, lane = tid & 63;
    const int m15 = lane & 15, q = lane >> 4;
    const int wr = wave >> 1, wc = wave & 1;           // 2x2 wave grid
    const int row0 = blockIdx.x * BM, col0 = blockIdx.y * BN;
    const f16* Wb = Wt + (size_t)blk * C_ * C_;
    const float* bias = ball + (size_t)blk * C_;

    // staging source: chunk ch (8 rows x 64k, 1KB): lane l loads row ch*8+(l>>3),
    // col-block (l&7)^((l>>3)&7) so LDS slot base+l*16 holds the swizzled layout
    const int srow = lane >> 3;
    const int scol = ((lane & 7) ^ (srow & 7)) << 3;   // halfs
    const f16* aSrc[4]; const f16* wSrc[4];
    f16* aDst[2][4]; f16* wDst[2][4];
    #pragma unroll
    for (int i = 0; i < 4; ++i) {
        int ch = wave * 4 + i;
        aSrc[i] = A  + (size_t)(row0 + ch * 8 + srow) * C_ + scol;
        wSrc[i] = Wb + (size_t)(col0 + ch * 8 + srow) * C_ + scol;
        aDst[0][i] = &As[0][ch * 512]; aDst[1][i] = &As[1][ch * 512];
        wDst[0][i] = &Ws[0][ch * 512]; wDst[1][i] = &Ws[1][ch * 512];
    }

    f32x4 acc[4][4];
    #pragma unroll
    for (int i = 0; i < 4; ++i)
        #pragma unroll
        for (int j = 0; j < 4; ++j) acc[i][j] = (f32x4)0.f;

    // prefetch tile 0 -> buf 0
    #pragma unroll
    for (int i = 0; i < 4; ++i) { gl16(aSrc[i], aDst[0][i]); gl16(wSrc[i], wDst[0][i]); }

    for (int kt = 0; kt < C_ / BK; ++kt) {
        __syncthreads();   // drains this tile's loads (vmcnt) + syncs buffer reuse
        int cur = kt & 1;
        if (kt + 1 < C_ / BK) {
            int nxt = cur ^ 1, koff = (kt + 1) * BK;
            #pragma unroll
            for (int i = 0; i < 4; ++i) {
                gl16(aSrc[i] + koff, aDst[nxt][i]);
                gl16(wSrc[i] + koff, wDst[nxt][i]);
            }
        }
        const f16* Ab = &As[cur][0];
        const f16* Bb = &Ws[cur][0];
        #pragma unroll
        for (int kk = 0; kk < BK; kk += 32) {
            f16x8 af[4], bf[4];
            #pragma unroll
            for (int i = 0; i < 4; ++i) {
                int r = wr * 64 + i * 16 + m15;
                int c = (kk >> 3) + q;
                af[i] = *(const f16x8*)&Ab[r * 64 + ((c ^ (r & 7)) << 3)];
            }
            #pragma unroll
            for (int j = 0; j < 4; ++j) {
                int r = wc * 64 + j * 16 + m15;
                int c = (kk >> 3) + q;
                bf[j] = *(const f16x8*)&Bb[r * 64 + ((c ^ (r & 7)) << 3)];
            }
            #pragma unroll
            for (int i = 0; i < 4; ++i)
                #pragma unroll
                for (int j = 0; j < 4; ++j)
                    acc[i][j] = __builtin_amdgcn_mfma_f32_16x16x32_f16(af[i], bf[j], acc[i][j], 0, 0, 0);
        }
    }

    // epilogue: C/D layout col=lane&15, row=quad*4+reg (HW-verified, dtype-indep)
    float bcol[4];
    #pragma unroll
    for (int j = 0; j < 4; ++j) bcol[j] = bias[col0 + wc * 64 + j * 16 + m15];
    #pragma unroll
    for (int i = 0; i < 4; ++i) {
        #pragma unroll
        for (int r = 0; r < 4; ++r) {
            int row = row0 + wr * 64 + i * 16 + q * 4 + r;
            #pragma unroll
            for (int j = 0; j < 4; ++j) {
                int col = col0 + wc * 64 + j * 16 + m15;
                out[(size_t)row * C_ + col] = (f16)gelu_f(acc[i][j][r] + bcol[j]);
            }
        }
    }
}

// ---------- global mean pool (fp16 in, fp32 out) ----------
__global__ __launch_bounds__(256) void pool_kernel(const f16* __restrict__ nx,
                                                   float* __restrict__ pooled) {
    int b = blockIdx.x;
    int c = blockIdx.y * 256 + threadIdx.x;
    const f16* p = nx + (size_t)b * HW_ * C_ + c;
    float s = 0.f;
    #pragma unroll 4
    for (int i = 0; i < HW_; ++i) s += (float)p[(size_t)i * C_];
    pooled[b * C_ + c] = s * (1.f / 196.f);
}

// ---------- gating MLP + softmax over anchors (fp32 weights from d_in) ----------
__global__ __launch_bounds__(256) void gate_kernel(const float* __restrict__ pooled,
    const float* __restrict__ fc1w, const float* __restrict__ fc1b,
    const float* __restrict__ fc2w, const float* __restrict__ fc2b,
    int t, float* __restrict__ gates)
{
    __shared__ float sp[C_];
    __shared__ float sh[HID_];
    const int b = blockIdx.x, tid = threadIdx.x;
    sp[tid]       = pooled[b * C_ + tid];
    sp[tid + 256] = pooled[b * C_ + tid + 256];
    __syncthreads();
    if (tid < HID_) {
        const float* w = fc1w + (size_t)t * C_ * HID_ + tid;
        float s = fc1b[t * HID_ + tid];
        for (int c = 0; c < C_; ++c) s += sp[c] * w[(size_t)c * HID_];
        sh[tid] = gelu_f(s);
    }
    __syncthreads();
    #pragma unroll
    for (int cc = 0; cc < 2; ++cc) {
        int c = tid + cc * 256;
        const float* w2 = fc2w + (size_t)t * HID_ * (3 * C_) + c;
        float l0 = fc2b[t * 3 * C_ + c];
        float l1 = fc2b[t * 3 * C_ + C_ + c];
        float l2 = fc2b[t * 3 * C_ + 2 * C_ + c];
        for (int j = 0; j < HID_; ++j) {
            float h = sh[j];
            const float* r = w2 + (size_t)j * 3 * C_;
            l0 += h * r[0];
            l1 += h * r[C_];
            l2 += h * r[2 * C_];
        }
        float m  = fmaxf(l0, fmaxf(l1, l2));
        float e0 = expf(l0 - m), e1 = expf(l1 - m), e2 = expf(l2 - m);
        float inv = 1.f / (e0 + e1 + e2);
        gates[(size_t)b * 3 * C_ + c]          = e0 * inv;
        gates[(size_t)b * 3 * C_ + C_ + c]     = e1 * inv;
        gates[(size_t)b * 3 * C_ + 2 * C_ + c] = e2 * inv;
    }
}

// ---------- nx += gamma * sum_a gates[b,a,c]*anchor_a ; t==2 also writes fp32 out ----------
__global__ __launch_bounds__(256) void routed_add_kernel(f16* __restrict__ nx,
    const f16* __restrict__ a0, const f16* __restrict__ a1, const f16* __restrict__ a2,
    const float* __restrict__ gates, const float* __restrict__ gammas, int t,
    float* __restrict__ outf)
{
    int idx = blockIdx.x * 256 + threadIdx.x;
    int c = idx & (C_ - 1);
    int b = idx / (HW_ * C_);
    const float* g = gates + (size_t)b * 3 * C_;
    float gamma = gammas[t];
    float v = (float)nx[idx] + gamma * (g[c] * (float)a0[idx] + g[C_ + c] * (float)a1[idx]
                                        + g[2 * C_ + c] * (float)a2[idx]);
    if (outf) outf[idx] = v;      // final target: fp32 to d_out
    else      nx[idx] = (f16)v;   // intermediate: fp16 in-place
}

extern "C" void kernel_launch(void* const* d_in, const int* in_sizes, int n_in,
                              void* d_out, int out_size, void* d_ws, size_t ws_size,
                              hipStream_t stream)
{
    const float* x      = (const float*)d_in[0];
    const float* blockw = (const float*)d_in[1];
    const float* blockb = (const float*)d_in[2];
    const float* fc1w   = (const float*)d_in[3];
    const float* fc1b   = (const float*)d_in[4];
    const float* fc2w   = (const float*)d_in[5];
    const float* fc2b   = (const float*)d_in[6];
    const float* gammas = (const float*)d_in[7];
    float* out = (float*)d_out;

    const size_t NB = (size_t)M_ * C_;            // 3,211,264 elems/activation
    f16* Wt = (f16*)d_ws;                          // 18*512*512 halfs = 9.44MB
    f16* P0 = Wt + (size_t)NBLK * C_ * C_;
    f16* P1 = P0 + NB;
    f16* A0 = P0 + 2 * NB;
    f16* A1 = P0 + 3 * NB;
    f16* A2 = P0 + 4 * NB;
    float* pooled = (float*)(P0 + 5 * NB);
    float* gates  = pooled + B_ * C_;

    conv_w<<<dim3(8, 8, NBLK), 256, 0, stream>>>(blockw, Wt);
    conv_x<<<(int)(NB / 256), 256, 0, stream>>>(x, P1);

    // x(fp16)=P1 feeds block 0; anchors (blocks 1,4,9 outputs) pinned A0/A1/A2
    const f16* ins[NBLK]  = {P1, P0, A0, P0, P1, A1, P0, P1, P0, P1, A2, P0, P1, P0, P1, P0, P1, P0};
    f16*       outs[NBLK] = {P0, A0, P0, P1, A1, P0, P1, P0, P1, A2, P0, P1, P0, P1, P0, P1, P0, P1};

    for (int i = 0; i < NBLK; ++i) {
        gemm_f16<<<dim3(M_ / BM, C_ / BN), 256, 0, stream>>>(
            ins[i], Wt, blockb, i, outs[i]);
        int t = (i == 11) ? 0 : (i == 14) ? 1 : (i == 17) ? 2 : -1;
        if (t >= 0) {
            pool_kernel<<<dim3(B_, 2), 256, 0, stream>>>(outs[i], pooled);
            gate_kernel<<<B_, 256, 0, stream>>>(pooled, fc1w, fc1b, fc2w, fc2b, t, gates);
            routed_add_kernel<<<(int)(NB / 256), 256, 0, stream>>>(
                outs[i], A0, A1, A2, gates, gammas, t,
                (t == 2) ? out : (float*)nullptr);
        }
    }
}

// Round 6
// 466.956 us; speedup vs baseline: 1.2003x; 1.2003x over previous
//
#include <hip/hip_runtime.h>

#define B_   32
#define HW_  196
#define C_   512
#define M_   (B_*HW_)    // 6272
#define HID_ 128
#define NBLK 18

typedef _Float16 f16;
typedef _Float16 f16x8 __attribute__((ext_vector_type(8)));
typedef float    f32x4 __attribute__((ext_vector_type(4)));

__device__ __forceinline__ float gelu_f(float x) {
    float t = tanhf(0.7978845608028654f * (x + 0.044715f * x * x * x));
    return 0.5f * x * (1.0f + t);
}

// async global->LDS, 16B per lane; LDS dest = wave-uniform base + lane*16
__device__ __forceinline__ void gl16(const void* g, void* l) {
    __builtin_amdgcn_global_load_lds((const __attribute__((address_space(1))) unsigned*)g,
                                     (__attribute__((address_space(3))) unsigned*)l, 16, 0, 0);
}

// ---------- weights: fp32 [blk][k][n] -> fp16 transposed [blk][n][k] ----------
__global__ __launch_bounds__(256) void conv_w(const float* __restrict__ W,
                                              f16* __restrict__ Wt) {
    __shared__ f16 sh[64][72];
    const int blk = blockIdx.z, k0 = blockIdx.x * 64, n0 = blockIdx.y * 64;
    const int tid = threadIdx.x;
    const float* Wb = W + (size_t)blk * C_ * C_;
    #pragma unroll
    for (int i = 0; i < 4; ++i) {
        int s = tid + i * 256, r = s >> 4, c4 = (s & 15) << 2;
        float4 v = *(const float4*)&Wb[(size_t)(k0 + r) * C_ + n0 + c4];
        sh[r][c4 + 0] = (f16)v.x; sh[r][c4 + 1] = (f16)v.y;
        sh[r][c4 + 2] = (f16)v.z; sh[r][c4 + 3] = (f16)v.w;
    }
    __syncthreads();
    #pragma unroll
    for (int i = 0; i < 2; ++i) {
        int s = tid + i * 256, r = s >> 3, c8 = (s & 7) << 3;
        f16x8 o;
        #pragma unroll
        for (int j = 0; j < 8; ++j) o[j] = sh[c8 + j][r];
        *(f16x8*)&Wt[(size_t)blk * C_ * C_ + (size_t)(n0 + r) * C_ + k0 + c8] = o;
    }
}

// ---------- x: fp32 -> fp16 ----------
__global__ __launch_bounds__(256) void conv_x(const float* __restrict__ in,
                                              f16* __restrict__ out) {
    int i = blockIdx.x * 256 + threadIdx.x;
    out[i] = (f16)in[i];
}

// ---------- MFMA GEMM: out = gelu(A[M,K]@W_blk[K,N] + b) ----------
// 64x64x64 tile, 4 waves (2x2 grid, each wave 32x32 via 2x2 16x16x32 frags).
// grid 98x8 = 784 blocks -> ~12 waves/CU (occupancy is the binding constraint).
// global_load_lds staging with XOR-16B swizzle, double-buffered LDS (32 KB).
#define BM 64
#define BN 64
#define BK 64
// LDS layout (halfs): tile[r][c-block] at r*64 + ((c ^ (r&7))<<3), r<64, c<8
__global__ __launch_bounds__(256) void gemm_f16(
    const f16* __restrict__ A, const f16* __restrict__ Wt,
    const float* __restrict__ ball, int blk, f16* __restrict__ out)
{
    __shared__ f16 As[2][BM * BK];
    __shared__ f16 Ws[2][BN * BK];
    const int tid = threadIdx.x;
    const int wave = tid >> 6, lane = tid & 63;
    const int m15 = lane & 15, q = lane >> 4;
    const int wr = wave >> 1, wc = wave & 1;           // 2x2 wave grid, 32x32 tiles
    const int row0 = blockIdx.x * BM, col0 = blockIdx.y * BN;
    const f16* Wb = Wt + (size_t)blk * C_ * C_;
    const float* bias = ball + (size_t)blk * C_;

    // staging: chunk ch = 8 rows x 64k (1KB). lane l loads row ch*8+(l>>3),
    // col-block (l&7)^(row&7), landing at LDS base+l*16 = swizzled layout.
    const int srow = lane >> 3;
    const int scol = ((lane & 7) ^ (srow & 7)) << 3;   // halfs
    const f16* aSrc[2]; const f16* wSrc[2];
    f16* aDst[2][2]; f16* wDst[2][2];
    #pragma unroll
    for (int i = 0; i < 2; ++i) {
        int ch = wave * 2 + i;                          // 8 chunks cover 64 rows
        aSrc[i] = A  + (size_t)(row0 + ch * 8 + srow) * C_ + scol;
        wSrc[i] = Wb + (size_t)(col0 + ch * 8 + srow) * C_ + scol;
        aDst[0][i] = &As[0][ch * 512]; aDst[1][i] = &As[1][ch * 512];
        wDst[0][i] = &Ws[0][ch * 512]; wDst[1][i] = &Ws[1][ch * 512];
    }

    f32x4 acc[2][2];
    #pragma unroll
    for (int i = 0; i < 2; ++i)
        #pragma unroll
        for (int j = 0; j < 2; ++j) acc[i][j] = (f32x4)0.f;

    // prefetch tile 0 -> buf 0
    #pragma unroll
    for (int i = 0; i < 2; ++i) { gl16(aSrc[i], aDst[0][i]); gl16(wSrc[i], wDst[0][i]); }

    for (int kt = 0; kt < C_ / BK; ++kt) {
        __syncthreads();   // drains this tile's loads + syncs buffer reuse
        int cur = kt & 1;
        if (kt + 1 < C_ / BK) {
            int nxt = cur ^ 1, koff = (kt + 1) * BK;
            #pragma unroll
            for (int i = 0; i < 2; ++i) {
                gl16(aSrc[i] + koff, aDst[nxt][i]);
                gl16(wSrc[i] + koff, wDst[nxt][i]);
            }
        }
        const f16* Ab = &As[cur][0];
        const f16* Bb = &Ws[cur][0];
        #pragma unroll
        for (int kk = 0; kk < BK; kk += 32) {
            f16x8 af[2], bf[2];
            #pragma unroll
            for (int i = 0; i < 2; ++i) {
                int r = wr * 32 + i * 16 + m15;
                int c = (kk >> 3) + q;
                af[i] = *(const f16x8*)&Ab[r * 64 + ((c ^ (r & 7)) << 3)];
            }
            #pragma unroll
            for (int j = 0; j < 2; ++j) {
                int r = wc * 32 + j * 16 + m15;
                int c = (kk >> 3) + q;
                bf[j] = *(const f16x8*)&Bb[r * 64 + ((c ^ (r & 7)) << 3)];
            }
            #pragma unroll
            for (int i = 0; i < 2; ++i)
                #pragma unroll
                for (int j = 0; j < 2; ++j)
                    acc[i][j] = __builtin_amdgcn_mfma_f32_16x16x32_f16(af[i], bf[j], acc[i][j], 0, 0, 0);
        }
    }

    // epilogue: C/D layout col=lane&15, row=quad*4+reg (HW-verified, dtype-indep)
    float bcol[2];
    #pragma unroll
    for (int j = 0; j < 2; ++j) bcol[j] = bias[col0 + wc * 32 + j * 16 + m15];
    #pragma unroll
    for (int i = 0; i < 2; ++i) {
        #pragma unroll
        for (int r = 0; r < 4; ++r) {
            int row = row0 + wr * 32 + i * 16 + q * 4 + r;
            #pragma unroll
            for (int j = 0; j < 2; ++j) {
                int col = col0 + wc * 32 + j * 16 + m15;
                out[(size_t)row * C_ + col] = (f16)gelu_f(acc[i][j][r] + bcol[j]);
            }
        }
    }
}

// ---------- global mean pool (fp16 in, fp32 out) ----------
__global__ __launch_bounds__(256) void pool_kernel(const f16* __restrict__ nx,
                                                   float* __restrict__ pooled) {
    int b = blockIdx.x;
    int c = blockIdx.y * 256 + threadIdx.x;
    const f16* p = nx + (size_t)b * HW_ * C_ + c;
    float s = 0.f;
    #pragma unroll 4
    for (int i = 0; i < HW_; ++i) s += (float)p[(size_t)i * C_];
    pooled[b * C_ + c] = s * (1.f / 196.f);
}

// ---------- gating MLP + softmax over anchors (fp32 weights from d_in) ----------
__global__ __launch_bounds__(256) void gate_kernel(const float* __restrict__ pooled,
    const float* __restrict__ fc1w, const float* __restrict__ fc1b,
    const float* __restrict__ fc2w, const float* __restrict__ fc2b,
    int t, float* __restrict__ gates)
{
    __shared__ float sp[C_];
    __shared__ float sh[HID_];
    const int b = blockIdx.x, tid = threadIdx.x;
    sp[tid]       = pooled[b * C_ + tid];
    sp[tid + 256] = pooled[b * C_ + tid + 256];
    __syncthreads();
    if (tid < HID_) {
        const float* w = fc1w + (size_t)t * C_ * HID_ + tid;
        float s = fc1b[t * HID_ + tid];
        for (int c = 0; c < C_; ++c) s += sp[c] * w[(size_t)c * HID_];
        sh[tid] = gelu_f(s);
    }
    __syncthreads();
    #pragma unroll
    for (int cc = 0; cc < 2; ++cc) {
        int c = tid + cc * 256;
        const float* w2 = fc2w + (size_t)t * HID_ * (3 * C_) + c;
        float l0 = fc2b[t * 3 * C_ + c];
        float l1 = fc2b[t * 3 * C_ + C_ + c];
        float l2 = fc2b[t * 3 * C_ + 2 * C_ + c];
        for (int j = 0; j < HID_; ++j) {
            float h = sh[j];
            const float* r = w2 + (size_t)j * 3 * C_;
            l0 += h * r[0];
            l1 += h * r[C_];
            l2 += h * r[2 * C_];
        }
        float m  = fmaxf(l0, fmaxf(l1, l2));
        float e0 = expf(l0 - m), e1 = expf(l1 - m), e2 = expf(l2 - m);
        float inv = 1.f / (e0 + e1 + e2);
        gates[(size_t)b * 3 * C_ + c]          = e0 * inv;
        gates[(size_t)b * 3 * C_ + C_ + c]     = e1 * inv;
        gates[(size_t)b * 3 * C_ + 2 * C_ + c] = e2 * inv;
    }
}

// ---------- nx += gamma * sum_a gates[b,a,c]*anchor_a ; t==2 also writes fp32 out ----------
__global__ __launch_bounds__(256) void routed_add_kernel(f16* __restrict__ nx,
    const f16* __restrict__ a0, const f16* __restrict__ a1, const f16* __restrict__ a2,
    const float* __restrict__ gates, const float* __restrict__ gammas, int t,
    float* __restrict__ outf)
{
    int idx = blockIdx.x * 256 + threadIdx.x;
    int c = idx & (C_ - 1);
    int b = idx / (HW_ * C_);
    const float* g = gates + (size_t)b * 3 * C_;
    float gamma = gammas[t];
    float v = (float)nx[idx] + gamma * (g[c] * (float)a0[idx] + g[C_ + c] * (float)a1[idx]
                                        + g[2 * C_ + c] * (float)a2[idx]);
    if (outf) outf[idx] = v;      // final target: fp32 to d_out
    else      nx[idx] = (f16)v;   // intermediate: fp16 in-place
}

extern "C" void kernel_launch(void* const* d_in, const int* in_sizes, int n_in,
                              void* d_out, int out_size, void* d_ws, size_t ws_size,
                              hipStream_t stream)
{
    const float* x      = (const float*)d_in[0];
    const float* blockw = (const float*)d_in[1];
    const float* blockb = (const float*)d_in[2];
    const float* fc1w   = (const float*)d_in[3];
    const float* fc1b   = (const float*)d_in[4];
    const float* fc2w   = (const float*)d_in[5];
    const float* fc2b   = (const float*)d_in[6];
    const float* gammas = (const float*)d_in[7];
    float* out = (float*)d_out;

    const size_t NB = (size_t)M_ * C_;            // 3,211,264 elems/activation
    f16* Wt = (f16*)d_ws;                          // 18*512*512 halfs = 9.44MB
    f16* P0 = Wt + (size_t)NBLK * C_ * C_;
    f16* P1 = P0 + NB;
    f16* A0 = P0 + 2 * NB;
    f16* A1 = P0 + 3 * NB;
    f16* A2 = P0 + 4 * NB;
    float* pooled = (float*)(P0 + 5 * NB);
    float* gates  = pooled + B_ * C_;

    conv_w<<<dim3(8, 8, NBLK), 256, 0, stream>>>(blockw, Wt);
    conv_x<<<(int)(NB / 256), 256, 0, stream>>>(x, P1);

    // x(fp16)=P1 feeds block 0; anchors (blocks 1,4,9 outputs) pinned A0/A1/A2
    const f16* ins[NBLK]  = {P1, P0, A0, P0, P1, A1, P0, P1, P0, P1, A2, P0, P1, P0, P1, P0, P1, P0};
    f16*       outs[NBLK] = {P0, A0, P0, P1, A1, P0, P1, P0, P1, A2, P0, P1, P0, P1, P0, P1, P0, P1};

    for (int i = 0; i < NBLK; ++i) {
        gemm_f16<<<dim3(M_ / BM, C_ / BN), 256, 0, stream>>>(
            ins[i], Wt, blockb, i, outs[i]);
        int t = (i == 11) ? 0 : (i == 14) ? 1 : (i == 17) ? 2 : -1;
        if (t >= 0) {
            pool_kernel<<<dim3(B_, 2), 256, 0, stream>>>(outs[i], pooled);
            gate_kernel<<<B_, 256, 0, stream>>>(pooled, fc1w, fc1b, fc2w, fc2b, t, gates);
            routed_add_kernel<<<(int)(NB / 256), 256, 0, stream>>>(
                outs[i], A0, A1, A2, gates, gammas, t,
                (t == 2) ? out : (float*)nullptr);
        }
    }
}